// Round 4
// baseline (325.708 us; speedup 1.0000x reference)
//
#include <hip/hip_runtime.h>
#include <hip/hip_bf16.h>

#define Bc 2
#define Hc 16
#define Sc 2048
#define Dc 1024

typedef __attribute__((ext_vector_type(8))) short s16x8;
typedef __attribute__((ext_vector_type(4))) float f32x4;

static __device__ __forceinline__ unsigned short f2bf(float f) {
    union { float f; unsigned u; } x; x.f = f;
    unsigned r = x.u + 0x7fffu + ((x.u >> 16) & 1u);
    return (unsigned short)(r >> 16);
}

// ReLU + scale + fp32->bf16 + [B,S,D] -> [B*H, S, 64] head-major relayout
__global__ __launch_bounds__(256) void relu_cvt_heads(const float* __restrict__ src,
                                                      unsigned short* __restrict__ dst,
                                                      float scale) {
    long i = ((long)blockIdx.x * blockDim.x + threadIdx.x) * 4;
    if (i >= (long)Bc * Sc * Dc) return;
    int dh = (int)(i & 63);
    int h  = (int)((i >> 6) & (Hc - 1));
    int s  = (int)((i >> 10) & (Sc - 1));
    int b  = (int)(i >> 21);
    float4 v = *reinterpret_cast<const float4*>(src + i);
    long o = (((long)b * Hc + h) * Sc + s) * 64 + dh;
    ushort4 w;
    w.x = f2bf(fmaxf(v.x, 0.f) * scale);
    w.y = f2bf(fmaxf(v.y, 0.f) * scale);
    w.z = f2bf(fmaxf(v.z, 0.f) * scale);
    w.w = f2bf(fmaxf(v.w, 0.f) * scale);
    *reinterpret_cast<ushort4*>(dst + o) = w;
}

// ReLU + cvt + transpose V: [B,S,D] -> VT[B*H][64 dh][S] bf16 (tiled via LDS)
__global__ __launch_bounds__(256) void relu_cvt_vT(const float* __restrict__ v,
                                                   unsigned short* __restrict__ vt) {
    __shared__ unsigned short lds[64][66];   // [s][dh], stride 66 (conflict-break)
    const int tid = threadIdx.x;
    const int st = blockIdx.x & (Sc / 64 - 1);   // 32 s-tiles
    const int bh = blockIdx.x >> 5;
    const int b = bh >> 4, h = bh & 15;
#pragma unroll
    for (int i = 0; i < 4; ++i) {
        int srow = (tid >> 4) + i * 16;
        int scol = (tid & 15) * 4;
        float4 x = *(const float4*)(v + ((long)b * Sc + st * 64 + srow) * Dc + h * 64 + scol);
        lds[srow][scol + 0] = f2bf(fmaxf(x.x, 0.f));
        lds[srow][scol + 1] = f2bf(fmaxf(x.y, 0.f));
        lds[srow][scol + 2] = f2bf(fmaxf(x.z, 0.f));
        lds[srow][scol + 3] = f2bf(fmaxf(x.w, 0.f));
    }
    __syncthreads();
#pragma unroll
    for (int i = 0; i < 2; ++i) {
        int dh = (tid >> 3) + i * 32;
        int sc = (tid & 7) * 8;
        union { unsigned short u[8]; s16x8 v8; } o;
#pragma unroll
        for (int j = 0; j < 8; ++j) o.u[j] = lds[sc + j][dh];
        *(s16x8*)(vt + ((long)bh * 64 + dh) * Sc + st * 64 + sc) = o.v8;
    }
}

// plain fp32->bf16 (for W)
__global__ __launch_bounds__(256) void cvt_w(const float* __restrict__ src,
                                             unsigned short* __restrict__ dst) {
    long i = ((long)blockIdx.x * blockDim.x + threadIdx.x) * 4;
    if (i >= (long)Dc * Dc) return;
    float4 v = *reinterpret_cast<const float4*>(src + i);
    ushort4 w;
    w.x = f2bf(v.x); w.y = f2bf(v.y); w.z = f2bf(v.z); w.w = f2bf(v.w);
    *reinterpret_cast<ushort4*>(dst + i) = w;
}

// Flash attention, swapped-operand form, no LDS, static softmax max (scores>=0
// because q,k are ReLU'd => exp2-domain scores in [0,~7], P in [1,128]).
// 1 wave/block, QBLK=16, KVBLK=32, 4 waves/EU, XCD-swizzled for K/V L2 locality.
// S^T = K·Q^T  (C: row=kv, col=q=lane&15); O^T = V^T·P^T (C: row=dh, col=q).
__global__ __launch_bounds__(64, 4) void attn16(const unsigned short* __restrict__ qh,
                                                const unsigned short* __restrict__ kh,
                                                const unsigned short* __restrict__ vt,
                                                unsigned short* __restrict__ xout) {
    const int l = threadIdx.x;
    const int r = l & 15, g = l >> 4;
    // XCD swizzle: 4096 blocks, 8 XCDs -> 512 consecutive jobs (4 bh) per XCD.
    const int job = (blockIdx.x & 7) * 512 + (blockIdx.x >> 3);
    const int qt = job & (Sc / 16 - 1);   // 128 q-tiles per bh
    const int bh = job >> 7;

    const unsigned short* Qp = qh + ((long)bh * Sc + qt * 16) * 64;
    const unsigned short* Kp = kh + (long)bh * Sc * 64;
    const unsigned short* Vp = vt + (long)bh * 64 * Sc;

    // Q^T B-frags (hoisted): lane holds Q[qt*16 + r][g*8+i (+32*half)]
    s16x8 qb0 = *(const s16x8*)(Qp + r * 64 + g * 8);
    s16x8 qb1 = *(const s16x8*)(Qp + r * 64 + 32 + g * 8);

    f32x4 acc[4];
#pragma unroll
    for (int d = 0; d < 4; ++d) acc[d] = (f32x4){0.f, 0.f, 0.f, 0.f};
    float denom = 0.f;

    // P^T B-frag shuffle sources: word w of lane(r,g) comes from
    // lane (2*(g&1)+(w>>1))*16+r, pk-pair (w&1), kv-half hi=(g>=2).
    const int srcA = ((g & 1) << 5) + r;   // words 0,1
    const int srcB = srcA + 16;            // words 2,3
    const bool hi = (g >= 2);

    auto ldk = [&](int kv0, s16x8* ka) {
        ka[0] = *(const s16x8*)(Kp + (kv0 + r) * 64 + g * 8);
        ka[1] = *(const s16x8*)(Kp + (kv0 + r) * 64 + 32 + g * 8);
        ka[2] = *(const s16x8*)(Kp + (kv0 + 16 + r) * 64 + g * 8);
        ka[3] = *(const s16x8*)(Kp + (kv0 + 16 + r) * 64 + 32 + g * 8);
    };
    auto ldv = [&](int kv0, s16x8* va) {
#pragma unroll
        for (int d = 0; d < 4; ++d)
            va[d] = *(const s16x8*)(Vp + (d * 16 + r) * Sc + kv0 + g * 8);
    };

    auto step = [&](const s16x8* ka, const s16x8* va) {
        const f32x4 z = {0.f, 0.f, 0.f, 0.f};
        __builtin_amdgcn_s_setprio(1);
        f32x4 st0 = __builtin_amdgcn_mfma_f32_16x16x32_bf16(ka[1], qb1, z, 0, 0, 0);
        st0 = __builtin_amdgcn_mfma_f32_16x16x32_bf16(ka[0], qb0, st0, 0, 0, 0);
        f32x4 st1 = __builtin_amdgcn_mfma_f32_16x16x32_bf16(ka[3], qb1, z, 0, 0, 0);
        st1 = __builtin_amdgcn_mfma_f32_16x16x32_bf16(ka[2], qb0, st1, 0, 0, 0);
        __builtin_amdgcn_s_setprio(0);
        // static-max softmax numerators (scores >= 0)
        float e00 = exp2f(st0[0]), e01 = exp2f(st0[1]);
        float e02 = exp2f(st0[2]), e03 = exp2f(st0[3]);
        float e10 = exp2f(st1[0]), e11 = exp2f(st1[1]);
        float e12 = exp2f(st1[2]), e13 = exp2f(st1[3]);
        denom += ((e00 + e01) + (e02 + e03)) + ((e10 + e11) + (e12 + e13));
        // bf16 pack via round-bit + v_perm (hi16 of each f32), pairs along kv
        unsigned u00 = __builtin_bit_cast(unsigned, e00) + 0x8000u;
        unsigned u01 = __builtin_bit_cast(unsigned, e01) + 0x8000u;
        unsigned u02 = __builtin_bit_cast(unsigned, e02) + 0x8000u;
        unsigned u03 = __builtin_bit_cast(unsigned, e03) + 0x8000u;
        unsigned u10 = __builtin_bit_cast(unsigned, e10) + 0x8000u;
        unsigned u11 = __builtin_bit_cast(unsigned, e11) + 0x8000u;
        unsigned u12 = __builtin_bit_cast(unsigned, e12) + 0x8000u;
        unsigned u13 = __builtin_bit_cast(unsigned, e13) + 0x8000u;
        int pk00 = (int)__builtin_amdgcn_perm(u01, u00, 0x07060302u);  // kv 4g,4g+1
        int pk01 = (int)__builtin_amdgcn_perm(u03, u02, 0x07060302u);  // kv 4g+2,4g+3
        int pk10 = (int)__builtin_amdgcn_perm(u11, u10, 0x07060302u);  // kv 16+4g..
        int pk11 = (int)__builtin_amdgcn_perm(u13, u12, 0x07060302u);
        int a0 = __shfl(pk00, srcA), b0 = __shfl(pk01, srcA);
        int a1 = __shfl(pk10, srcA), b1 = __shfl(pk11, srcA);
        int c0 = __shfl(pk00, srcB), d0 = __shfl(pk01, srcB);
        int c1 = __shfl(pk10, srcB), d1 = __shfl(pk11, srcB);
        union { int w[4]; s16x8 v8; } bp;
        bp.w[0] = hi ? a1 : a0;
        bp.w[1] = hi ? b1 : b0;
        bp.w[2] = hi ? c1 : c0;
        bp.w[3] = hi ? d1 : d0;
        __builtin_amdgcn_s_setprio(1);
#pragma unroll
        for (int d = 0; d < 4; ++d)
            acc[d] = __builtin_amdgcn_mfma_f32_16x16x32_bf16(va[d], bp.v8, acc[d], 0, 0, 0);
        __builtin_amdgcn_s_setprio(0);
    };

    // register double-buffered main loop (prefetch next kv-tile during compute)
    s16x8 kaA[4], vaA[4], kaB[4], vaB[4];
    ldk(0, kaA); ldv(0, vaA);
    for (int t = 0; t < Sc / 32; t += 2) {
        ldk((t + 1) * 32, kaB); ldv((t + 1) * 32, vaB);
        step(kaA, vaA);
        int n2 = ((t + 2) & (Sc / 32 - 1)) * 32;   // wraps to 0 on last iter (harmless)
        ldk(n2, kaA); ldv(n2, vaA);
        step(kaB, vaB);
    }

    // epilogue: cross-lane denominator reduce (sum over g), scattered bf16 stores
    const int b = bh >> 4, h = bh & 15;
    float dn = denom;
    dn += __shfl_xor(dn, 16);
    dn += __shfl_xor(dn, 32);
    const float inv = 1.0f / dn;   // lane-aligned: col q = r
    unsigned short* Xrow = xout + ((long)b * Sc + qt * 16 + r) * Dc + h * 64;
#pragma unroll
    for (int dt = 0; dt < 4; ++dt)
#pragma unroll
        for (int j = 0; j < 4; ++j)
            Xrow[dt * 16 + g * 4 + j] = f2bf(acc[dt][j] * inv);
}

// Output projection: out = relu(X @ W^T + b). 4 waves/block, 64x64 tile.
__global__ __launch_bounds__(256) void proj64(const unsigned short* __restrict__ X,
                                              const unsigned short* __restrict__ Wb,
                                              const float* __restrict__ bias,
                                              float* __restrict__ out) {
    const int l = threadIdx.x & 63, wv = threadIdx.x >> 6;
    const int r = l & 15, g = l >> 4;
    const int nb = blockIdx.x & 15;   // N/64
    const int mb = blockIdx.x >> 4;   // M/64
    const unsigned short* Xp = X + ((long)(mb * 64 + wv * 16 + r)) * Dc;
    const unsigned short* W0 = Wb + ((long)(nb * 64 + r)) * Dc;
    f32x4 acc[4];
#pragma unroll
    for (int nt = 0; nt < 4; ++nt) acc[nt] = (f32x4){0.f, 0.f, 0.f, 0.f};
#pragma unroll 2
    for (int k = 0; k < Dc; k += 32) {
        s16x8 a = *(const s16x8*)(Xp + k + g * 8);
#pragma unroll
        for (int nt = 0; nt < 4; ++nt) {
            s16x8 bf = *(const s16x8*)(W0 + (long)nt * 16 * Dc + k + g * 8);
            acc[nt] = __builtin_amdgcn_mfma_f32_16x16x32_bf16(a, bf, acc[nt], 0, 0, 0);
        }
    }
#pragma unroll
    for (int nt = 0; nt < 4; ++nt) {
        const float bv = bias[nb * 64 + nt * 16 + r];
#pragma unroll
        for (int j = 0; j < 4; ++j)
            out[((long)(mb * 64 + wv * 16 + g * 4 + j)) * Dc + nb * 64 + nt * 16 + r] =
                fmaxf(acc[nt][j] + bv, 0.f);
    }
}

extern "C" void kernel_launch(void* const* d_in, const int* in_sizes, int n_in,
                              void* d_out, int out_size, void* d_ws, size_t ws_size,
                              hipStream_t stream) {
    const float* q    = (const float*)d_in[0];
    const float* k    = (const float*)d_in[1];
    const float* v    = (const float*)d_in[2];
    const float* w    = (const float*)d_in[3];
    const float* bias = (const float*)d_in[4];
    float* out = (float*)d_out;

    unsigned short* ws = (unsigned short*)d_ws;
    unsigned short* qh = ws;                   // 4194304 bf16
    unsigned short* kh = qh + 4194304;
    unsigned short* vt = kh + 4194304;         // V^T: [B*H][64][2048]
    unsigned short* wb = vt + 4194304;         // 1048576 bf16
    unsigned short* X  = wb + 1048576;         // 4194304 bf16

    // fold softmax scale (1/sqrt(64)) and log2(e) into Q: scores in exp2 domain
    const float QSCALE = 0.125f * 1.44269504088896340736f;
    relu_cvt_heads<<<4096, 256, 0, stream>>>(q, qh, QSCALE);
    relu_cvt_heads<<<4096, 256, 0, stream>>>(k, kh, 1.0f);
    relu_cvt_vT<<<1024, 256, 0, stream>>>(v, vt);
    cvt_w<<<1024, 256, 0, stream>>>(w, wb);
    attn16<<<Bc * Hc * (Sc / 16), 64, 0, stream>>>(qh, kh, vt, X);
    proj64<<<(Bc * Sc / 64) * (Dc / 64), 256, 0, stream>>>(X, wb, bias, out);
}

// Round 5
// 213.571 us; speedup vs baseline: 1.5251x; 1.5251x over previous
//
#include <hip/hip_runtime.h>
#include <hip/hip_bf16.h>

#define Bc 2
#define Hc 16
#define Sc 2048
#define Dc 1024

typedef __attribute__((ext_vector_type(8))) short s16x8;
typedef __attribute__((ext_vector_type(4))) float f32x4;

static __device__ __forceinline__ unsigned short f2bf(float f) {
    union { float f; unsigned u; } x; x.f = f;
    unsigned r = x.u + 0x7fffu + ((x.u >> 16) & 1u);
    return (unsigned short)(r >> 16);
}

// ReLU + scale + fp32->bf16 + [B,S,D] -> [B*H, S, 64] head-major relayout
__global__ __launch_bounds__(256) void relu_cvt_heads(const float* __restrict__ src,
                                                      unsigned short* __restrict__ dst,
                                                      float scale) {
    long i = ((long)blockIdx.x * blockDim.x + threadIdx.x) * 4;
    if (i >= (long)Bc * Sc * Dc) return;
    int dh = (int)(i & 63);
    int h  = (int)((i >> 6) & (Hc - 1));
    int s  = (int)((i >> 10) & (Sc - 1));
    int b  = (int)(i >> 21);
    float4 v = *reinterpret_cast<const float4*>(src + i);
    long o = (((long)b * Hc + h) * Sc + s) * 64 + dh;
    ushort4 w;
    w.x = f2bf(fmaxf(v.x, 0.f) * scale);
    w.y = f2bf(fmaxf(v.y, 0.f) * scale);
    w.z = f2bf(fmaxf(v.z, 0.f) * scale);
    w.w = f2bf(fmaxf(v.w, 0.f) * scale);
    *reinterpret_cast<ushort4*>(dst + o) = w;
}

// ReLU + cvt + transpose V: [B,S,D] -> VT[B*H][64 dh][S] bf16 (tiled via LDS)
__global__ __launch_bounds__(256) void relu_cvt_vT(const float* __restrict__ v,
                                                   unsigned short* __restrict__ vt) {
    __shared__ unsigned short lds[64][66];   // [s][dh], stride 66 (conflict-break)
    const int tid = threadIdx.x;
    const int st = blockIdx.x & (Sc / 64 - 1);   // 32 s-tiles
    const int bh = blockIdx.x >> 5;
    const int b = bh >> 4, h = bh & 15;
#pragma unroll
    for (int i = 0; i < 4; ++i) {
        int srow = (tid >> 4) + i * 16;
        int scol = (tid & 15) * 4;
        float4 x = *(const float4*)(v + ((long)b * Sc + st * 64 + srow) * Dc + h * 64 + scol);
        lds[srow][scol + 0] = f2bf(fmaxf(x.x, 0.f));
        lds[srow][scol + 1] = f2bf(fmaxf(x.y, 0.f));
        lds[srow][scol + 2] = f2bf(fmaxf(x.z, 0.f));
        lds[srow][scol + 3] = f2bf(fmaxf(x.w, 0.f));
    }
    __syncthreads();
#pragma unroll
    for (int i = 0; i < 2; ++i) {
        int dh = (tid >> 3) + i * 32;
        int sc = (tid & 7) * 8;
        union { unsigned short u[8]; s16x8 v8; } o;
#pragma unroll
        for (int j = 0; j < 8; ++j) o.u[j] = lds[sc + j][dh];
        *(s16x8*)(vt + ((long)bh * 64 + dh) * Sc + st * 64 + sc) = o.v8;
    }
}

// plain fp32->bf16 (for W)
__global__ __launch_bounds__(256) void cvt_w(const float* __restrict__ src,
                                             unsigned short* __restrict__ dst) {
    long i = ((long)blockIdx.x * blockDim.x + threadIdx.x) * 4;
    if (i >= (long)Dc * Dc) return;
    float4 v = *reinterpret_cast<const float4*>(src + i);
    ushort4 w;
    w.x = f2bf(v.x); w.y = f2bf(v.y); w.z = f2bf(v.z); w.w = f2bf(v.w);
    *reinterpret_cast<ushort4*>(dst + i) = w;
}

// Flash attention, swapped-operand form, no LDS, static softmax max (scores>=0
// because q,k are ReLU'd => exp2-domain scores in [0,~7], P in [1,128]).
// 1 wave/block, QBLK=32 (2 q-16-tiles), KVBLK=32, XCD-swizzled block mapping:
// 2048 blocks -> 256 consecutive jobs (2 bh, ~1MB K/V) per XCD L2.
// S^T = K·Q^T  (C: row=kv, col=q=lane&15); O^T = V^T·P^T (C: row=dh, col=q).
__global__ __launch_bounds__(64) void attn32(const unsigned short* __restrict__ qh,
                                             const unsigned short* __restrict__ kh,
                                             const unsigned short* __restrict__ vt,
                                             unsigned short* __restrict__ xout) {
    const int l = threadIdx.x;
    const int r = l & 15, g = l >> 4;
    // XCD swizzle (bijective: 2048 % 8 == 0)
    const int job = (blockIdx.x & 7) * (2048 / 8) + (blockIdx.x >> 3);
    const int qt = job & (Sc / 32 - 1);   // 64 q-blocks per bh
    const int bh = job >> 6;

    const unsigned short* Qp = qh + ((long)bh * Sc + qt * 32) * 64;
    const unsigned short* Kp = kh + (long)bh * Sc * 64;
    const unsigned short* Vp = vt + (long)bh * 64 * Sc;

    // Q^T B-frags (hoisted): B[k=dh][col=q]: lane holds Q[q0+r][g*8+i (+32*half)]
    s16x8 qb[2][2];
#pragma unroll
    for (int qi = 0; qi < 2; ++qi) {
        qb[qi][0] = *(const s16x8*)(Qp + (qi * 16 + r) * 64 + g * 8);
        qb[qi][1] = *(const s16x8*)(Qp + (qi * 16 + r) * 64 + 32 + g * 8);
    }

    f32x4 acc[2][4];
#pragma unroll
    for (int qi = 0; qi < 2; ++qi)
#pragma unroll
        for (int d = 0; d < 4; ++d) acc[qi][d] = (f32x4){0.f, 0.f, 0.f, 0.f};
    float denom[2] = {0.f, 0.f};

    // P^T B-frag shuffle sources: word w of lane(r,g) comes from
    // lane (2*(g&1)+(w>>1))*16+r, pk-pair (w&1), kv-half hi=(g>=2).
    const int srcA = ((g & 1) << 5) + r;   // words 0,1
    const int srcB = srcA + 16;            // words 2,3
    const bool hi = (g >= 2);

    auto ldk = [&](int kv0, s16x8* ka) {
        ka[0] = *(const s16x8*)(Kp + (kv0 + r) * 64 + g * 8);
        ka[1] = *(const s16x8*)(Kp + (kv0 + r) * 64 + 32 + g * 8);
        ka[2] = *(const s16x8*)(Kp + (kv0 + 16 + r) * 64 + g * 8);
        ka[3] = *(const s16x8*)(Kp + (kv0 + 16 + r) * 64 + 32 + g * 8);
    };
    auto ldv = [&](int kv0, s16x8* va) {
#pragma unroll
        for (int d = 0; d < 4; ++d)
            va[d] = *(const s16x8*)(Vp + (d * 16 + r) * Sc + kv0 + g * 8);
    };

    auto step = [&](const s16x8* ka, const s16x8* va) {
#pragma unroll
        for (int qi = 0; qi < 2; ++qi) {
            const f32x4 z = {0.f, 0.f, 0.f, 0.f};
            // S^T tiles: kv 0..15 and 16..31 for this 32-kv step
            f32x4 st0 = __builtin_amdgcn_mfma_f32_16x16x32_bf16(ka[1], qb[qi][1], z, 0, 0, 0);
            st0 = __builtin_amdgcn_mfma_f32_16x16x32_bf16(ka[0], qb[qi][0], st0, 0, 0, 0);
            f32x4 st1 = __builtin_amdgcn_mfma_f32_16x16x32_bf16(ka[3], qb[qi][1], z, 0, 0, 0);
            st1 = __builtin_amdgcn_mfma_f32_16x16x32_bf16(ka[2], qb[qi][0], st1, 0, 0, 0);
            // static-max softmax numerators (scores >= 0)
            float e00 = exp2f(st0[0]), e01 = exp2f(st0[1]);
            float e02 = exp2f(st0[2]), e03 = exp2f(st0[3]);
            float e10 = exp2f(st1[0]), e11 = exp2f(st1[1]);
            float e12 = exp2f(st1[2]), e13 = exp2f(st1[3]);
            denom[qi] += ((e00 + e01) + (e02 + e03)) + ((e10 + e11) + (e12 + e13));
            // bf16 pack via round-bit + v_perm (hi16 of each f32), pairs along kv
            unsigned u00 = __builtin_bit_cast(unsigned, e00) + 0x8000u;
            unsigned u01 = __builtin_bit_cast(unsigned, e01) + 0x8000u;
            unsigned u02 = __builtin_bit_cast(unsigned, e02) + 0x8000u;
            unsigned u03 = __builtin_bit_cast(unsigned, e03) + 0x8000u;
            unsigned u10 = __builtin_bit_cast(unsigned, e10) + 0x8000u;
            unsigned u11 = __builtin_bit_cast(unsigned, e11) + 0x8000u;
            unsigned u12 = __builtin_bit_cast(unsigned, e12) + 0x8000u;
            unsigned u13 = __builtin_bit_cast(unsigned, e13) + 0x8000u;
            int pk00 = (int)__builtin_amdgcn_perm(u01, u00, 0x07060302u);  // kv 4g,4g+1
            int pk01 = (int)__builtin_amdgcn_perm(u03, u02, 0x07060302u);  // kv 4g+2,4g+3
            int pk10 = (int)__builtin_amdgcn_perm(u11, u10, 0x07060302u);  // kv 16+4g..
            int pk11 = (int)__builtin_amdgcn_perm(u13, u12, 0x07060302u);
            int a0 = __shfl(pk00, srcA), b0 = __shfl(pk01, srcA);
            int a1 = __shfl(pk10, srcA), b1 = __shfl(pk11, srcA);
            int c0 = __shfl(pk00, srcB), d0 = __shfl(pk01, srcB);
            int c1 = __shfl(pk10, srcB), d1 = __shfl(pk11, srcB);
            union { int w[4]; s16x8 v8; } bp;
            bp.w[0] = hi ? a1 : a0;
            bp.w[1] = hi ? b1 : b0;
            bp.w[2] = hi ? c1 : c0;
            bp.w[3] = hi ? d1 : d0;
#pragma unroll
            for (int d = 0; d < 4; ++d)
                acc[qi][d] = __builtin_amdgcn_mfma_f32_16x16x32_bf16(va[d], bp.v8, acc[qi][d], 0, 0, 0);
        }
    };

    // register double-buffered main loop (prefetch next kv-tile during compute)
    s16x8 kaA[4], vaA[4], kaB[4], vaB[4];
    ldk(0, kaA); ldv(0, vaA);
    for (int t = 0; t < Sc / 32; t += 2) {
        ldk((t + 1) * 32, kaB); ldv((t + 1) * 32, vaB);
        step(kaA, vaA);
        int n2 = ((t + 2) & (Sc / 32 - 1)) * 32;   // wraps to 0 on last iter (harmless)
        ldk(n2, kaA); ldv(n2, vaA);
        step(kaB, vaB);
    }

    // epilogue: one cross-lane denominator reduce per q-tile, then scattered bf16 stores
    const int b = bh >> 4, h = bh & 15;
#pragma unroll
    for (int qi = 0; qi < 2; ++qi) {
        float d = denom[qi];
        d += __shfl_xor(d, 16);
        d += __shfl_xor(d, 32);
        const float inv = 1.0f / d;   // lane-aligned: col q = r
        unsigned short* Xrow = xout + ((long)b * Sc + qt * 32 + qi * 16 + r) * Dc + h * 64;
#pragma unroll
        for (int dt = 0; dt < 4; ++dt)
#pragma unroll
            for (int j = 0; j < 4; ++j)
                Xrow[dt * 16 + g * 4 + j] = f2bf(acc[qi][dt][j] * inv);
    }
}

// Output projection: out = relu(X @ W^T + b). 4 waves/block, 64x64 tile.
__global__ __launch_bounds__(256) void proj64(const unsigned short* __restrict__ X,
                                              const unsigned short* __restrict__ Wb,
                                              const float* __restrict__ bias,
                                              float* __restrict__ out) {
    const int l = threadIdx.x & 63, wv = threadIdx.x >> 6;
    const int r = l & 15, g = l >> 4;
    const int nb = blockIdx.x & 15;   // N/64
    const int mb = blockIdx.x >> 4;   // M/64
    const unsigned short* Xp = X + ((long)(mb * 64 + wv * 16 + r)) * Dc;
    const unsigned short* W0 = Wb + ((long)(nb * 64 + r)) * Dc;
    f32x4 acc[4];
#pragma unroll
    for (int nt = 0; nt < 4; ++nt) acc[nt] = (f32x4){0.f, 0.f, 0.f, 0.f};
#pragma unroll 2
    for (int k = 0; k < Dc; k += 32) {
        s16x8 a = *(const s16x8*)(Xp + k + g * 8);
#pragma unroll
        for (int nt = 0; nt < 4; ++nt) {
            s16x8 bf = *(const s16x8*)(W0 + (long)nt * 16 * Dc + k + g * 8);
            acc[nt] = __builtin_amdgcn_mfma_f32_16x16x32_bf16(a, bf, acc[nt], 0, 0, 0);
        }
    }
#pragma unroll
    for (int nt = 0; nt < 4; ++nt) {
        const float bv = bias[nb * 64 + nt * 16 + r];
#pragma unroll
        for (int j = 0; j < 4; ++j)
            out[((long)(mb * 64 + wv * 16 + g * 4 + j)) * Dc + nb * 64 + nt * 16 + r] =
                fmaxf(acc[nt][j] + bv, 0.f);
    }
}

extern "C" void kernel_launch(void* const* d_in, const int* in_sizes, int n_in,
                              void* d_out, int out_size, void* d_ws, size_t ws_size,
                              hipStream_t stream) {
    const float* q    = (const float*)d_in[0];
    const float* k    = (const float*)d_in[1];
    const float* v    = (const float*)d_in[2];
    const float* w    = (const float*)d_in[3];
    const float* bias = (const float*)d_in[4];
    float* out = (float*)d_out;

    unsigned short* ws = (unsigned short*)d_ws;
    unsigned short* qh = ws;                   // 4194304 bf16
    unsigned short* kh = qh + 4194304;
    unsigned short* vt = kh + 4194304;         // V^T: [B*H][64][2048]
    unsigned short* wb = vt + 4194304;         // 1048576 bf16
    unsigned short* X  = wb + 1048576;         // 4194304 bf16

    // fold softmax scale (1/sqrt(64)) and log2(e) into Q: scores in exp2 domain
    const float QSCALE = 0.125f * 1.44269504088896340736f;
    relu_cvt_heads<<<4096, 256, 0, stream>>>(q, qh, QSCALE);
    relu_cvt_heads<<<4096, 256, 0, stream>>>(k, kh, 1.0f);
    relu_cvt_vT<<<1024, 256, 0, stream>>>(v, vt);
    cvt_w<<<1024, 256, 0, stream>>>(w, wb);
    attn32<<<Bc * Hc * (Sc / 32), 64, 0, stream>>>(qh, kh, vt, X);
    proj64<<<(Bc * Sc / 64) * (Dc / 64), 256, 0, stream>>>(X, wb, bias, out);
}